// Round 7
// baseline (664.254 us; speedup 1.0000x reference)
//
#include <hip/hip_runtime.h>
#include <hip/hip_bf16.h>
#include <stdint.h>

#define N_NODES 150000
#define C_IN 32
#define C_OUT 64
#define K_TAPS 27
#define K_PAD 28                    // taps padded to 28 (tap 27 = zero weights, pad-row gather)
#define PF 3
#define NSTEP 7                     // 28 / 4 waves
#define NSLOTS 32
#define Y_STRIDE 150016             // bf16 y row stride (keeps 16B alignment)

#define TRANS_BLOCKS 2344           // 2344*64 = 150016 nodes (incl. pad row)
#define WPREP_BLOCKS 224            // 224*256 >= 64*32*28 = 57344
#define N_TILES 4688                // 4688*32 = 150016 nodes
#define FUSED_BLOCKS 1024           // all co-resident: VGPR<=128 -> >=4 blk/CU -> 1024
#define CHUNKS_PER_ROW 18750        // 150000/8
#define TOTAL_CHUNKS (C_OUT * CHUNKS_PER_ROW)
#define WS_NEED 28934656ull         // xT + A_frag + stats/counter + yb

typedef __attribute__((ext_vector_type(8))) __bf16 bf16x8;
typedef __attribute__((ext_vector_type(4))) float f32x4;
typedef __attribute__((ext_vector_type(4))) uint32_t u32x4;

__device__ __forceinline__ ushort f2bf(float f) {
    union { float f; uint32_t u; } v; v.f = f;
    uint32_t u = v.u;
    return (ushort)((u + 0x7FFFu + ((u >> 16) & 1u)) >> 16);
}

// ---------------------------------------------------------------------------
// Kernel 1 (fused prep): blocks [0,2344) transpose x -> xT (bf16, zero pad row).
// Blocks [2344,2568) repack W (28 taps, tap 27 zeroed), zero stats + barrier ctr.
// ---------------------------------------------------------------------------
__global__ __launch_bounds__(256) void k_prep(const float* __restrict__ x,
                                              ushort* __restrict__ xT,
                                              const float* __restrict__ W,
                                              ushort* __restrict__ A_frag,
                                              float* __restrict__ stats) {
    int t = threadIdx.x;
    int b = blockIdx.x;
    if (b < TRANS_BLOCKS) {
        __shared__ float tile[32][65];
        int nb = b * 64;
        int nl = t & 63, i4 = t >> 6;
#pragma unroll
        for (int rep = 0; rep < 8; ++rep) {
            int i = rep * 4 + i4;
            int n = nb + nl;
            tile[i][nl] = (n < N_NODES) ? x[(size_t)i * N_NODES + n] : 0.0f;
        }
        __syncthreads();
        int nr = t >> 2, c0 = (t & 3) * 8;
        int n = nb + nr;
        if (n <= N_NODES) {
            uint32_t w[4];
#pragma unroll
            for (int j = 0; j < 4; ++j) {
                ushort lo = f2bf(tile[c0 + 2 * j][nr]);
                ushort hi = f2bf(tile[c0 + 2 * j + 1][nr]);
                w[j] = (uint32_t)lo | ((uint32_t)hi << 16);
            }
            *reinterpret_cast<uint4*>(xT + (size_t)n * 32 + c0) =
                make_uint4(w[0], w[1], w[2], w[3]);
        }
    } else {
        // A_frag[(k*4+m)*512 + lane*8 + j] = W[m*16+(lane&15)][(lane>>4)*8+j][k]
        int tid = (b - TRANS_BLOCKS) * 256 + t;
        if (tid < NSLOTS * 128 + 128) stats[tid] = 0.0f;  // covers barrier counter too
        if (tid < C_OUT * C_IN * K_PAD) {
            int j = tid & 7;
            int ln = (tid >> 3) & 63;
            int km = tid >> 9;
            int m = km & 3;
            int k = km >> 2;
            int o = m * 16 + (ln & 15);
            int i = (ln >> 4) * 8 + j;
            A_frag[tid] =
                (k < K_TAPS) ? f2bf(W[o * (C_IN * K_TAPS) + i * K_TAPS + k]) : (ushort)0;
        }
    }
}

// ---------------------------------------------------------------------------
// Kernel 2 (persistent fused conv + grid barrier + BN/ReLU).
// Phase 1: each block loops over tiles (blockIdx, +1024, ...): round-6 hot loop.
// Barrier: fence -> atomic arrive -> spin (all 1024 blocks co-resident by
// launch_bounds contract). Phase 2: finalize stats, stream yb -> out.
// ---------------------------------------------------------------------------
__global__ __launch_bounds__(256, 4) void k_fused(
    const ushort* __restrict__ xT, const ushort* __restrict__ A_frag,
    const int* __restrict__ neigh, float* __restrict__ out,
    ushort* __restrict__ yb, float* __restrict__ stats, int* __restrict__ barrier_ctr,
    const float* __restrict__ gamma, const float* __restrict__ beta, int use_bf16) {
    __shared__ int soff[32 * K_PAD];
    __shared__ float sacc[C_OUT * 32];
    __shared__ float s_sc[C_OUT], s_sh[C_OUT];
    int t = threadIdx.x;
    int wid = t >> 6, lane = t & 63;
    int l15 = lane & 15, quad = lane >> 4;
    int qoff = quad << 4;
    const char* xTb = (const char*)xT;
    const char* aB = (const char*)A_frag + (size_t)lane * 16;

    // ---------------- Phase 1: conv over this block's tiles ----------------
    for (int tile = blockIdx.x; tile < N_TILES; tile += FUSED_BLOCKS) {
        int nb = tile * 32;
        __syncthreads();  // protect soff/sacc reuse across tile iterations
        for (int j = t; j < 32 * K_PAD; j += 256) {
            int n = j / K_PAD;
            int kk = j - n * K_PAD;
            int ng = nb + n;
            int idx = (kk < K_TAPS && ng < N_NODES) ? neigh[(size_t)ng * K_TAPS + kk]
                                                    : N_NODES;
            soff[j] = idx << 6;
        }
        __syncthreads();

        f32x4 acc[4][2];
#pragma unroll
        for (int m = 0; m < 4; ++m)
#pragma unroll
            for (int g = 0; g < 2; ++g) acc[m][g] = (f32x4){0.f, 0.f, 0.f, 0.f};

        bf16x8 bb[PF][2], aa[PF][4];
#pragma unroll
        for (int s = 0; s < PF; ++s) {
            int k = wid + 4 * s;
#pragma unroll
            for (int g = 0; g < 2; ++g)
                bb[s][g] = *reinterpret_cast<const bf16x8*>(
                    xTb + (uint32_t)soff[(g * 16 + l15) * K_PAD + k] + qoff);
#pragma unroll
            for (int m = 0; m < 4; ++m)
                aa[s][m] =
                    *reinterpret_cast<const bf16x8*>(aB + ((size_t)(k * 4 + m) << 10));
        }

#pragma unroll
        for (int s = 0; s < NSTEP; ++s) {
            int cur = s % PF;
#pragma unroll
            for (int m = 0; m < 4; ++m)
#pragma unroll
                for (int g = 0; g < 2; ++g)
                    acc[m][g] = __builtin_amdgcn_mfma_f32_16x16x32_bf16(
                        aa[cur][m], bb[cur][g], acc[m][g], 0, 0, 0);
            if (s < NSTEP - PF) {
                int kn = wid + 4 * (s + PF);
#pragma unroll
                for (int g = 0; g < 2; ++g)
                    bb[cur][g] = *reinterpret_cast<const bf16x8*>(
                        xTb + (uint32_t)soff[(g * 16 + l15) * K_PAD + kn] + qoff);
#pragma unroll
                for (int m = 0; m < 4; ++m)
                    aa[cur][m] = *reinterpret_cast<const bf16x8*>(
                        aB + ((size_t)(kn * 4 + m) << 10));
            }
        }

        // combine partials across the 4 K-split waves via LDS
        if (wid == 0) {
#pragma unroll
            for (int m = 0; m < 4; ++m)
#pragma unroll
                for (int g = 0; g < 2; ++g)
#pragma unroll
                    for (int r = 0; r < 4; ++r)
                        sacc[(m * 16 + quad * 4 + r) * 32 + g * 16 + l15] =
                            acc[m][g][r];
        }
        __syncthreads();
#pragma unroll
        for (int w = 1; w < 4; ++w) {
            if (wid == w) {
#pragma unroll
                for (int m = 0; m < 4; ++m)
#pragma unroll
                    for (int g = 0; g < 2; ++g)
#pragma unroll
                        for (int r = 0; r < 4; ++r)
                            sacc[(m * 16 + quad * 4 + r) * 32 + g * 16 + l15] +=
                                acc[m][g][r];
            }
            __syncthreads();
        }

        // y store (non-temporal)
        if (use_bf16) {
            int e0 = t * 8;
            int o = t >> 2;
            int n0 = (t & 3) * 8;
            uint32_t w[4];
#pragma unroll
            for (int j = 0; j < 4; ++j) {
                ushort lo = f2bf(sacc[e0 + 2 * j]);
                ushort hi = f2bf(sacc[e0 + 2 * j + 1]);
                w[j] = (uint32_t)lo | ((uint32_t)hi << 16);
            }
            u32x4 v = {w[0], w[1], w[2], w[3]};
            __builtin_nontemporal_store(
                v, reinterpret_cast<u32x4*>(yb + (size_t)o * Y_STRIDE + nb + n0));
        } else {
#pragma unroll
            for (int rep = 0; rep < 8; ++rep) {
                int idx = rep * 256 + t;
                int o = idx >> 5;
                int n = nb + (idx & 31);
                if (n < N_NODES)
                    __builtin_nontemporal_store(sacc[idx],
                                                &out[(size_t)o * N_NODES + n]);
            }
        }

        // stats (wave0)
        if (wid == 0) {
            int slot = tile & (NSLOTS - 1);
#pragma unroll
            for (int m = 0; m < 4; ++m) {
#pragma unroll
                for (int r = 0; r < 4; ++r) {
                    int o = m * 16 + quad * 4 + r;
                    float s = 0.f, sq = 0.f;
#pragma unroll
                    for (int g = 0; g < 2; ++g) {
                        float v = sacc[o * 32 + g * 16 + l15];
                        s += v;
                        sq += v * v;
                    }
#pragma unroll
                    for (int d = 1; d < 16; d <<= 1) {
                        s += __shfl_xor(s, d);
                        sq += __shfl_xor(sq, d);
                    }
                    if (l15 == 0) {
                        atomicAdd(&stats[slot * 128 + o], s);
                        atomicAdd(&stats[slot * 128 + 64 + o], sq);
                    }
                }
            }
        }
    }

    // ---------------- Grid barrier (all 1024 blocks co-resident) ----------------
    __threadfence();   // release: y stores + stats atomics visible device-wide
    __syncthreads();
    if (t == 0) {
        __hip_atomic_fetch_add(barrier_ctr, 1, __ATOMIC_ACQ_REL,
                               __HIP_MEMORY_SCOPE_AGENT);
        while (__hip_atomic_load(barrier_ctr, __ATOMIC_ACQUIRE,
                                 __HIP_MEMORY_SCOPE_AGENT) < FUSED_BLOCKS) {
            __builtin_amdgcn_s_sleep(8);
        }
    }
    __syncthreads();
    __threadfence();   // acquire: invalidate stale local caches before reading y/stats

    // ---------------- Phase 2: BN finalize + apply ----------------
    if (t < C_OUT) {
        float s = 0.f, sq = 0.f;
        for (int c = 0; c < NSLOTS; ++c) {
            s += __hip_atomic_load(&stats[c * 128 + t], __ATOMIC_RELAXED,
                                   __HIP_MEMORY_SCOPE_AGENT);
            sq += __hip_atomic_load(&stats[c * 128 + 64 + t], __ATOMIC_RELAXED,
                                    __HIP_MEMORY_SCOPE_AGENT);
        }
        const float invN = 1.0f / (float)N_NODES;
        float mean = s * invN;
        float var = sq * invN - mean * mean;
        float rstd = rsqrtf(var + 1e-3f);
        float sc = gamma[t] * rstd;
        s_sc[t] = sc;
        s_sh[t] = beta[t] - mean * sc;
    }
    __syncthreads();

    if (use_bf16) {
        for (int c = blockIdx.x * 256 + t; c < TOTAL_CHUNKS; c += FUSED_BLOCKS * 256) {
            int o = c / CHUNKS_PER_ROW;
            int pos = (c - o * CHUNKS_PER_ROW) * 8;
            float sc = s_sc[o], sh = s_sh[o];
            u32x4 v = __builtin_nontemporal_load(
                reinterpret_cast<const u32x4*>(yb + (size_t)o * Y_STRIDE + pos));
            f32x4 f0, f1;
#pragma unroll
            for (int j = 0; j < 2; ++j) {
                f0[2 * j] = __uint_as_float(v[j] << 16);
                f0[2 * j + 1] = __uint_as_float(v[j] & 0xffff0000u);
                f1[2 * j] = __uint_as_float(v[j + 2] << 16);
                f1[2 * j + 1] = __uint_as_float(v[j + 2] & 0xffff0000u);
            }
#pragma unroll
            for (int j = 0; j < 4; ++j) {
                f0[j] = fmaxf(fmaf(f0[j], sc, sh), 0.f);
                f1[j] = fmaxf(fmaf(f1[j], sc, sh), 0.f);
            }
            f32x4* op = reinterpret_cast<f32x4*>(out + (size_t)o * N_NODES + pos);
            __builtin_nontemporal_store(f0, op);
            __builtin_nontemporal_store(f1, op + 1);
        }
    } else {
        for (int c = blockIdx.x * 256 + t; c < TOTAL_CHUNKS; c += FUSED_BLOCKS * 256) {
            int o = c / CHUNKS_PER_ROW;
            int pos = (c - o * CHUNKS_PER_ROW) * 8;
            float sc = s_sc[o], sh = s_sh[o];
            f32x4* op = reinterpret_cast<f32x4*>(out + (size_t)o * N_NODES + pos);
            f32x4 f0 = op[0], f1 = op[1];
#pragma unroll
            for (int j = 0; j < 4; ++j) {
                f0[j] = fmaxf(fmaf(f0[j], sc, sh), 0.f);
                f1[j] = fmaxf(fmaf(f1[j], sc, sh), 0.f);
            }
            op[0] = f0;
            op[1] = f1;
        }
    }
}

extern "C" void kernel_launch(void* const* d_in, const int* in_sizes, int n_in,
                              void* d_out, int out_size, void* d_ws, size_t ws_size,
                              hipStream_t stream) {
    const float* data_in = (const float*)d_in[0];
    const int* neigh = (const int*)d_in[1];
    const float* W = (const float*)d_in[2];
    const float* gamma = (const float*)d_in[3];
    const float* beta = (const float*)d_in[4];
    float* out = (float*)d_out;

    char* ws = (char*)d_ws;
    ushort* xT = (ushort*)ws;                     // 150016*32*2 = 9,601,024 B
    ushort* A_frag = (ushort*)(ws + 9601024);     // 64*32*28*2  =   114,688 B
    float* stats = (float*)(ws + 9715712);        // 32*128 partials = 16,384 B
    int* barrier_ctr = (int*)(ws + 9715712 + NSLOTS * 128 * 4);  // zeroed by prep
    ushort* yb = (ushort*)(ws + 9732608);         // 64*150016*2 = 19,202,048 B

    int use_bf16 = (ws_size >= WS_NEED) ? 1 : 0;

    k_prep<<<TRANS_BLOCKS + WPREP_BLOCKS, 256, 0, stream>>>(data_in, xT, W, A_frag,
                                                            stats);
    k_fused<<<FUSED_BLOCKS, 256, 0, stream>>>(xT, A_frag, neigh, out, yb, stats,
                                              barrier_ctr, gamma, beta, use_bf16);
}

// Round 8
// 544.964 us; speedup vs baseline: 1.2189x; 1.2189x over previous
//
#include <hip/hip_runtime.h>
#include <hip/hip_bf16.h>
#include <stdint.h>

#define N_NODES 150000
#define C_IN 32
#define C_OUT 64
#define K_TAPS 27
#define K_PAD 28                    // taps padded to 28 (tap 27 = zero weights, pad-row gather)
#define PF 3
#define NSTEP 7                     // 28 / 4 waves
#define NSLOTS 32
#define Y_STRIDE 150016             // bf16 y row stride (keeps 16B alignment)

#define TRANS_BLOCKS 2344           // 2344*64 = 150016 nodes (incl. pad row)
#define WPREP_BLOCKS 224            // 224*256 >= 64*32*28 = 57344
#define N_TILES 4688                // 4688*32 = 150016 nodes
#define FUSED_BLOCKS 1024           // all co-resident: 4 blk/CU x 256 CU
#define CHUNKS_PER_ROW 18750        // 150000/8
#define TOTAL_CHUNKS (C_OUT * CHUNKS_PER_ROW)
#define WS_NEED 28934656ull         // xT + A_frag + stats/counter + yb

typedef __attribute__((ext_vector_type(8))) __bf16 bf16x8;
typedef __attribute__((ext_vector_type(4))) float f32x4;
typedef __attribute__((ext_vector_type(4))) uint32_t u32x4;

__device__ __forceinline__ ushort f2bf(float f) {
    union { float f; uint32_t u; } v; v.f = f;
    uint32_t u = v.u;
    return (ushort)((u + 0x7FFFu + ((u >> 16) & 1u)) >> 16);
}

// ---------------------------------------------------------------------------
// Kernel 1 (fused prep): blocks [0,2344) transpose x -> xT (bf16, zero pad row).
// Blocks [2344,2568) repack W (28 taps, tap 27 zeroed), zero stats + barrier ctr.
// ---------------------------------------------------------------------------
__global__ __launch_bounds__(256) void k_prep(const float* __restrict__ x,
                                              ushort* __restrict__ xT,
                                              const float* __restrict__ W,
                                              ushort* __restrict__ A_frag,
                                              float* __restrict__ stats) {
    int t = threadIdx.x;
    int b = blockIdx.x;
    if (b < TRANS_BLOCKS) {
        __shared__ float tile[32][65];
        int nb = b * 64;
        int nl = t & 63, i4 = t >> 6;
#pragma unroll
        for (int rep = 0; rep < 8; ++rep) {
            int i = rep * 4 + i4;
            int n = nb + nl;
            tile[i][nl] = (n < N_NODES) ? x[(size_t)i * N_NODES + n] : 0.0f;
        }
        __syncthreads();
        int nr = t >> 2, c0 = (t & 3) * 8;
        int n = nb + nr;
        if (n <= N_NODES) {
            uint32_t w[4];
#pragma unroll
            for (int j = 0; j < 4; ++j) {
                ushort lo = f2bf(tile[c0 + 2 * j][nr]);
                ushort hi = f2bf(tile[c0 + 2 * j + 1][nr]);
                w[j] = (uint32_t)lo | ((uint32_t)hi << 16);
            }
            *reinterpret_cast<uint4*>(xT + (size_t)n * 32 + c0) =
                make_uint4(w[0], w[1], w[2], w[3]);
        }
    } else {
        // A_frag[(k*4+m)*512 + lane*8 + j] = W[m*16+(lane&15)][(lane>>4)*8+j][k]
        int tid = (b - TRANS_BLOCKS) * 256 + t;
        if (tid < NSLOTS * 128 + 128) stats[tid] = 0.0f;  // covers barrier counter too
        if (tid < C_OUT * C_IN * K_PAD) {
            int j = tid & 7;
            int ln = (tid >> 3) & 63;
            int km = tid >> 9;
            int m = km & 3;
            int k = km >> 2;
            int o = m * 16 + (ln & 15);
            int i = (ln >> 4) * 8 + j;
            A_frag[tid] =
                (k < K_TAPS) ? f2bf(W[o * (C_IN * K_TAPS) + i * K_TAPS + k]) : (ushort)0;
        }
    }
}

// ---------------------------------------------------------------------------
// Kernel 2 (persistent fused conv + grid barrier + BN/ReLU).
// Barrier protocol (round-7 lesson): RELAXED polls (no per-poll cache
// invalidation), single ACQUIRE after exit. Release fence before arrive.
// ---------------------------------------------------------------------------
__global__ __launch_bounds__(256, 4) void k_fused(
    const ushort* __restrict__ xT, const ushort* __restrict__ A_frag,
    const int* __restrict__ neigh, float* __restrict__ out,
    ushort* __restrict__ yb, float* __restrict__ stats, int* __restrict__ barrier_ctr,
    const float* __restrict__ gamma, const float* __restrict__ beta, int use_bf16) {
    __shared__ int soff[32 * K_PAD];
    __shared__ float sacc[C_OUT * 32];
    __shared__ float s_sc[C_OUT], s_sh[C_OUT];
    int t = threadIdx.x;
    int wid = t >> 6, lane = t & 63;
    int l15 = lane & 15, quad = lane >> 4;
    int qoff = quad << 4;
    const char* xTb = (const char*)xT;
    const char* aB = (const char*)A_frag + (size_t)lane * 16;

    // ---------------- Phase 1: conv over this block's tiles ----------------
    for (int tile = blockIdx.x; tile < N_TILES; tile += FUSED_BLOCKS) {
        int nb = tile * 32;
        __syncthreads();  // protect soff/sacc reuse across tile iterations
        for (int j = t; j < 32 * K_PAD; j += 256) {
            int n = j / K_PAD;
            int kk = j - n * K_PAD;
            int ng = nb + n;
            int idx = (kk < K_TAPS && ng < N_NODES) ? neigh[(size_t)ng * K_TAPS + kk]
                                                    : N_NODES;
            soff[j] = idx << 6;
        }
        __syncthreads();

        f32x4 acc[4][2];
#pragma unroll
        for (int m = 0; m < 4; ++m)
#pragma unroll
            for (int g = 0; g < 2; ++g) acc[m][g] = (f32x4){0.f, 0.f, 0.f, 0.f};

        bf16x8 bb[PF][2], aa[PF][4];
#pragma unroll
        for (int s = 0; s < PF; ++s) {
            int k = wid + 4 * s;
#pragma unroll
            for (int g = 0; g < 2; ++g)
                bb[s][g] = *reinterpret_cast<const bf16x8*>(
                    xTb + (uint32_t)soff[(g * 16 + l15) * K_PAD + k] + qoff);
#pragma unroll
            for (int m = 0; m < 4; ++m)
                aa[s][m] =
                    *reinterpret_cast<const bf16x8*>(aB + ((size_t)(k * 4 + m) << 10));
        }

#pragma unroll
        for (int s = 0; s < NSTEP; ++s) {
            int cur = s % PF;
#pragma unroll
            for (int m = 0; m < 4; ++m)
#pragma unroll
                for (int g = 0; g < 2; ++g)
                    acc[m][g] = __builtin_amdgcn_mfma_f32_16x16x32_bf16(
                        aa[cur][m], bb[cur][g], acc[m][g], 0, 0, 0);
            if (s < NSTEP - PF) {
                int kn = wid + 4 * (s + PF);
#pragma unroll
                for (int g = 0; g < 2; ++g)
                    bb[cur][g] = *reinterpret_cast<const bf16x8*>(
                        xTb + (uint32_t)soff[(g * 16 + l15) * K_PAD + kn] + qoff);
#pragma unroll
                for (int m = 0; m < 4; ++m)
                    aa[cur][m] = *reinterpret_cast<const bf16x8*>(
                        aB + ((size_t)(kn * 4 + m) << 10));
            }
        }

        // combine partials across the 4 K-split waves via LDS
        if (wid == 0) {
#pragma unroll
            for (int m = 0; m < 4; ++m)
#pragma unroll
                for (int g = 0; g < 2; ++g)
#pragma unroll
                    for (int r = 0; r < 4; ++r)
                        sacc[(m * 16 + quad * 4 + r) * 32 + g * 16 + l15] =
                            acc[m][g][r];
        }
        __syncthreads();
#pragma unroll
        for (int w = 1; w < 4; ++w) {
            if (wid == w) {
#pragma unroll
                for (int m = 0; m < 4; ++m)
#pragma unroll
                    for (int g = 0; g < 2; ++g)
#pragma unroll
                        for (int r = 0; r < 4; ++r)
                            sacc[(m * 16 + quad * 4 + r) * 32 + g * 16 + l15] +=
                                acc[m][g][r];
            }
            __syncthreads();
        }

        // y store (non-temporal)
        if (use_bf16) {
            int e0 = t * 8;
            int o = t >> 2;
            int n0 = (t & 3) * 8;
            uint32_t w[4];
#pragma unroll
            for (int j = 0; j < 4; ++j) {
                ushort lo = f2bf(sacc[e0 + 2 * j]);
                ushort hi = f2bf(sacc[e0 + 2 * j + 1]);
                w[j] = (uint32_t)lo | ((uint32_t)hi << 16);
            }
            u32x4 v = {w[0], w[1], w[2], w[3]};
            __builtin_nontemporal_store(
                v, reinterpret_cast<u32x4*>(yb + (size_t)o * Y_STRIDE + nb + n0));
        } else {
#pragma unroll
            for (int rep = 0; rep < 8; ++rep) {
                int idx = rep * 256 + t;
                int o = idx >> 5;
                int n = nb + (idx & 31);
                if (n < N_NODES)
                    __builtin_nontemporal_store(sacc[idx],
                                                &out[(size_t)o * N_NODES + n]);
            }
        }

        // stats (wave0)
        if (wid == 0) {
            int slot = tile & (NSLOTS - 1);
#pragma unroll
            for (int m = 0; m < 4; ++m) {
#pragma unroll
                for (int r = 0; r < 4; ++r) {
                    int o = m * 16 + quad * 4 + r;
                    float s = 0.f, sq = 0.f;
#pragma unroll
                    for (int g = 0; g < 2; ++g) {
                        float v = sacc[o * 32 + g * 16 + l15];
                        s += v;
                        sq += v * v;
                    }
#pragma unroll
                    for (int d = 1; d < 16; d <<= 1) {
                        s += __shfl_xor(s, d);
                        sq += __shfl_xor(sq, d);
                    }
                    if (l15 == 0) {
                        atomicAdd(&stats[slot * 128 + o], s);
                        atomicAdd(&stats[slot * 128 + 64 + o], sq);
                    }
                }
            }
        }
    }

    // ---------------- Grid barrier (all 1024 blocks co-resident) ----------------
    __threadfence();   // release: drain y nt-stores + stats atomics device-wide
    __syncthreads();
    if (t == 0) {
        __hip_atomic_fetch_add(barrier_ctr, 1, __ATOMIC_RELEASE,
                               __HIP_MEMORY_SCOPE_AGENT);
        // RELAXED polls: no per-poll cache invalidation (round-7 bug).
        while (__hip_atomic_load(barrier_ctr, __ATOMIC_RELAXED,
                                 __HIP_MEMORY_SCOPE_AGENT) < FUSED_BLOCKS) {
            __builtin_amdgcn_s_sleep(64);
        }
        // single acquire to order phase-1 writes before phase-2 reads
        (void)__hip_atomic_load(barrier_ctr, __ATOMIC_ACQUIRE,
                                __HIP_MEMORY_SCOPE_AGENT);
    }
    __syncthreads();
    __threadfence();   // one per-block acquire fence (invalidate stale lines once)

    // ---------------- Phase 2: BN finalize + apply ----------------
    if (t < C_OUT) {
        float s = 0.f, sq = 0.f;
        for (int c = 0; c < NSLOTS; ++c) {
            s += __hip_atomic_load(&stats[c * 128 + t], __ATOMIC_RELAXED,
                                   __HIP_MEMORY_SCOPE_AGENT);
            sq += __hip_atomic_load(&stats[c * 128 + 64 + t], __ATOMIC_RELAXED,
                                    __HIP_MEMORY_SCOPE_AGENT);
        }
        const float invN = 1.0f / (float)N_NODES;
        float mean = s * invN;
        float var = sq * invN - mean * mean;
        float rstd = rsqrtf(var + 1e-3f);
        float sc = gamma[t] * rstd;
        s_sc[t] = sc;
        s_sh[t] = beta[t] - mean * sc;
    }
    __syncthreads();

    if (use_bf16) {
        for (int c = blockIdx.x * 256 + t; c < TOTAL_CHUNKS; c += FUSED_BLOCKS * 256) {
            int o = c / CHUNKS_PER_ROW;
            int pos = (c - o * CHUNKS_PER_ROW) * 8;
            float sc = s_sc[o], sh = s_sh[o];
            u32x4 v = __builtin_nontemporal_load(
                reinterpret_cast<const u32x4*>(yb + (size_t)o * Y_STRIDE + pos));
            f32x4 f0, f1;
#pragma unroll
            for (int j = 0; j < 2; ++j) {
                f0[2 * j] = __uint_as_float(v[j] << 16);
                f0[2 * j + 1] = __uint_as_float(v[j] & 0xffff0000u);
                f1[2 * j] = __uint_as_float(v[j + 2] << 16);
                f1[2 * j + 1] = __uint_as_float(v[j + 2] & 0xffff0000u);
            }
#pragma unroll
            for (int j = 0; j < 4; ++j) {
                f0[j] = fmaxf(fmaf(f0[j], sc, sh), 0.f);
                f1[j] = fmaxf(fmaf(f1[j], sc, sh), 0.f);
            }
            f32x4* op = reinterpret_cast<f32x4*>(out + (size_t)o * N_NODES + pos);
            __builtin_nontemporal_store(f0, op);
            __builtin_nontemporal_store(f1, op + 1);
        }
    } else {
        for (int c = blockIdx.x * 256 + t; c < TOTAL_CHUNKS; c += FUSED_BLOCKS * 256) {
            int o = c / CHUNKS_PER_ROW;
            int pos = (c - o * CHUNKS_PER_ROW) * 8;
            float sc = s_sc[o], sh = s_sh[o];
            f32x4* op = reinterpret_cast<f32x4*>(out + (size_t)o * N_NODES + pos);
            f32x4 f0 = op[0], f1 = op[1];
#pragma unroll
            for (int j = 0; j < 4; ++j) {
                f0[j] = fmaxf(fmaf(f0[j], sc, sh), 0.f);
                f1[j] = fmaxf(fmaf(f1[j], sc, sh), 0.f);
            }
            op[0] = f0;
            op[1] = f1;
        }
    }
}

extern "C" void kernel_launch(void* const* d_in, const int* in_sizes, int n_in,
                              void* d_out, int out_size, void* d_ws, size_t ws_size,
                              hipStream_t stream) {
    const float* data_in = (const float*)d_in[0];
    const int* neigh = (const int*)d_in[1];
    const float* W = (const float*)d_in[2];
    const float* gamma = (const float*)d_in[3];
    const float* beta = (const float*)d_in[4];
    float* out = (float*)d_out;

    char* ws = (char*)d_ws;
    ushort* xT = (ushort*)ws;                     // 150016*32*2 = 9,601,024 B
    ushort* A_frag = (ushort*)(ws + 9601024);     // 64*32*28*2  =   114,688 B
    float* stats = (float*)(ws + 9715712);        // 32*128 partials = 16,384 B
    int* barrier_ctr = (int*)(ws + 9715712 + NSLOTS * 128 * 4);  // zeroed by prep
    ushort* yb = (ushort*)(ws + 9732608);         // 64*150016*2 = 19,202,048 B

    int use_bf16 = (ws_size >= WS_NEED) ? 1 : 0;

    k_prep<<<TRANS_BLOCKS + WPREP_BLOCKS, 256, 0, stream>>>(data_in, xT, W, A_frag,
                                                            stats);
    k_fused<<<FUSED_BLOCKS, 256, 0, stream>>>(xT, A_frag, neigh, out, yb, stats,
                                              barrier_ctr, gamma, beta, use_bf16);
}

// Round 10
// 172.482 us; speedup vs baseline: 3.8511x; 3.1595x over previous
//
#include <hip/hip_runtime.h>
#include <hip/hip_bf16.h>
#include <stdint.h>

#define N_NODES 150000
#define C_IN 32
#define C_OUT 64
#define K_TAPS 27
#define K_PAD 28                    // taps padded to 28 (tap 27 = zero weights, pad-row gather)
#define PF 3
#define NSTEP 7                     // 28 / 4 waves
#define NSLOTS 32
#define Y_STRIDE 150016             // bf16 y row stride (keeps 16B alignment)

#define TRANS_BLOCKS 586            // 586*256 = 150016 nodes (incl. pad row), 4x64/block
#define WPREP_BLOCKS 56             // 56*1024 >= 64*32*28 = 57344
#define CONV_BLOCKS 4688            // 4688*32 = 150016 nodes, 4 waves/block (K-split)
#define CHUNKS_PER_ROW 18750        // 150000/8
#define BN_XBLOCKS 10               // 10*256 = 2560 threads/channel, grid-stride
#define WS_NEED 28934656ull         // xT + A_frag + stats + yb

typedef __attribute__((ext_vector_type(8))) __bf16 bf16x8;
typedef __attribute__((ext_vector_type(4))) float f32x4;
typedef __attribute__((ext_vector_type(4))) uint32_t u32x4;

__device__ __forceinline__ ushort f2bf(float f) {
    union { float f; uint32_t u; } v; v.f = f;
    uint32_t u = v.u;
    return (ushort)((u + 0x7FFFu + ((u >> 16) & 1u)) >> 16);
}

// ---------------------------------------------------------------------------
// Kernel 1 (fused prep): blocks [0,586) transpose x (32x150000 fp32) ->
// xT (150001 x 32 bf16, zero pad row), 4 sub-tiles of 64 nodes per block.
// Blocks [586,642) repack W (28 taps, tap 27 zeroed) and zero stats.
// Round-9 bug fixed: contiguous per-block tid coverage (tid mod 1024 spanned
// only [0,256) before -> 3/4 of A_frag stayed poisoned).
// ---------------------------------------------------------------------------
__global__ __launch_bounds__(256) void k_prep(const float* __restrict__ x,
                                              ushort* __restrict__ xT,
                                              const float* __restrict__ W,
                                              ushort* __restrict__ A_frag,
                                              float* __restrict__ stats) {
    int t = threadIdx.x;
    int b = blockIdx.x;
    if (b < TRANS_BLOCKS) {
        __shared__ float tile[32][65];
        int nl = t & 63, i4 = t >> 6;
        int nr = t >> 2, c0 = (t & 3) * 8;
#pragma unroll
        for (int sub = 0; sub < 4; ++sub) {
            int nb = b * 256 + sub * 64;
            if (sub) __syncthreads();  // protect tile reuse
#pragma unroll
            for (int rep = 0; rep < 8; ++rep) {
                int i = rep * 4 + i4;
                int n = nb + nl;
                tile[i][nl] = (n < N_NODES) ? x[(size_t)i * N_NODES + n] : 0.0f;
            }
            __syncthreads();
            int n = nb + nr;
            if (n <= N_NODES) {  // row N_NODES is the zero-pad row
                uint32_t w[4];
#pragma unroll
                for (int j = 0; j < 4; ++j) {
                    ushort lo = f2bf(tile[c0 + 2 * j][nr]);
                    ushort hi = f2bf(tile[c0 + 2 * j + 1][nr]);
                    w[j] = (uint32_t)lo | ((uint32_t)hi << 16);
                }
                *reinterpret_cast<uint4*>(xT + (size_t)n * 32 + c0) =
                    make_uint4(w[0], w[1], w[2], w[3]);
            }
        }
    } else {
        // A_frag[(k*4+m)*512 + lane*8 + j] = W[m*16+(lane&15)][(lane>>4)*8+j][k]
        int base = (b - TRANS_BLOCKS) * 1024;
#pragma unroll
        for (int rep = 0; rep < 4; ++rep) {
            int tid = base + rep * 256 + t;  // contiguous coverage [b*1024,(b+1)*1024)
            if (tid < NSLOTS * 128 + 128) stats[tid] = 0.0f;
            if (tid < C_OUT * C_IN * K_PAD) {
                int j = tid & 7;
                int ln = (tid >> 3) & 63;
                int km = tid >> 9;
                int m = km & 3;
                int k = km >> 2;
                int o = m * 16 + (ln & 15);
                int i = (ln >> 4) * 8 + j;
                A_frag[tid] = (k < K_TAPS)
                                  ? f2bf(W[o * (C_IN * K_TAPS) + i * K_TAPS + k])
                                  : (ushort)0;
            }
        }
    }
}

// ---------------------------------------------------------------------------
// Kernel 2: gather-GEMM, K-split over 4 waves. Block = 256 thr = 4 waves,
// 32 nodes/block; wave w handles taps {w, w+4, ..., w+24} (tap 27 zero-pad).
// BYTE-IDENTICAL hot loop to round 6 (measured: 72 us, FETCH 161 MB).
// ---------------------------------------------------------------------------
__global__ __launch_bounds__(256, 4) void k_conv(const ushort* __restrict__ xT,
                                                 const ushort* __restrict__ A_frag,
                                                 const int* __restrict__ neigh,
                                                 float* __restrict__ yf,
                                                 ushort* __restrict__ yb,
                                                 float* __restrict__ stats,
                                                 int use_bf16) {
    __shared__ int soff[32 * K_PAD];   // [node][28] pre-scaled byte offsets
    __shared__ float sacc[C_OUT * 32]; // [o][n] summed partials
    int t = threadIdx.x;
    int nb = blockIdx.x * 32;
    for (int j = t; j < 32 * K_PAD; j += 256) {
        int n = j / K_PAD;
        int kk = j - n * K_PAD;
        int ng = nb + n;
        int idx = (kk < K_TAPS && ng < N_NODES) ? neigh[(size_t)ng * K_TAPS + kk]
                                                : N_NODES;
        soff[j] = idx << 6;  // 64 B per xT row
    }
    __syncthreads();

    int wid = t >> 6, lane = t & 63;
    int l15 = lane & 15, quad = lane >> 4;
    int qoff = quad << 4;

    const char* xTb = (const char*)xT;
    const char* aB = (const char*)A_frag + (size_t)lane * 16;

    f32x4 acc[4][2];
#pragma unroll
    for (int m = 0; m < 4; ++m)
#pragma unroll
        for (int g = 0; g < 2; ++g) acc[m][g] = (f32x4){0.f, 0.f, 0.f, 0.f};

    bf16x8 bb[PF][2], aa[PF][4];
#pragma unroll
    for (int s = 0; s < PF; ++s) {
        int k = wid + 4 * s;
#pragma unroll
        for (int g = 0; g < 2; ++g)
            bb[s][g] = *reinterpret_cast<const bf16x8*>(
                xTb + (uint32_t)soff[(g * 16 + l15) * K_PAD + k] + qoff);
#pragma unroll
        for (int m = 0; m < 4; ++m)
            aa[s][m] = *reinterpret_cast<const bf16x8*>(aB + ((size_t)(k * 4 + m) << 10));
    }

#pragma unroll
    for (int s = 0; s < NSTEP; ++s) {
        int cur = s % PF;
#pragma unroll
        for (int m = 0; m < 4; ++m)
#pragma unroll
            for (int g = 0; g < 2; ++g)
                acc[m][g] = __builtin_amdgcn_mfma_f32_16x16x32_bf16(
                    aa[cur][m], bb[cur][g], acc[m][g], 0, 0, 0);
        if (s < NSTEP - PF) {
            int kn = wid + 4 * (s + PF);
#pragma unroll
            for (int g = 0; g < 2; ++g)
                bb[cur][g] = *reinterpret_cast<const bf16x8*>(
                    xTb + (uint32_t)soff[(g * 16 + l15) * K_PAD + kn] + qoff);
#pragma unroll
            for (int m = 0; m < 4; ++m)
                aa[cur][m] = *reinterpret_cast<const bf16x8*>(
                    aB + ((size_t)(kn * 4 + m) << 10));
        }
    }

    // combine partials: wave0 writes, waves 1..3 add in place
    if (wid == 0) {
#pragma unroll
        for (int m = 0; m < 4; ++m)
#pragma unroll
            for (int g = 0; g < 2; ++g)
#pragma unroll
                for (int r = 0; r < 4; ++r)
                    sacc[(m * 16 + quad * 4 + r) * 32 + g * 16 + l15] = acc[m][g][r];
    }
    __syncthreads();
#pragma unroll
    for (int w = 1; w < 4; ++w) {
        if (wid == w) {
#pragma unroll
            for (int m = 0; m < 4; ++m)
#pragma unroll
                for (int g = 0; g < 2; ++g)
#pragma unroll
                    for (int r = 0; r < 4; ++r)
                        sacc[(m * 16 + quad * 4 + r) * 32 + g * 16 + l15] +=
                            acc[m][g][r];
        }
        __syncthreads();
    }

    // cooperative y store (non-temporal)
    if (use_bf16) {
        int e0 = t * 8;
        int o = t >> 2;
        int n0 = (t & 3) * 8;
        uint32_t w[4];
#pragma unroll
        for (int j = 0; j < 4; ++j) {
            ushort lo = f2bf(sacc[e0 + 2 * j]);
            ushort hi = f2bf(sacc[e0 + 2 * j + 1]);
            w[j] = (uint32_t)lo | ((uint32_t)hi << 16);
        }
        u32x4 v = {w[0], w[1], w[2], w[3]};
        __builtin_nontemporal_store(
            v, reinterpret_cast<u32x4*>(yb + (size_t)o * Y_STRIDE + nb + n0));
    } else {
#pragma unroll
        for (int rep = 0; rep < 8; ++rep) {
            int idx = rep * 256 + t;
            int o = idx >> 5;
            int n = nb + (idx & 31);
            if (n < N_NODES)
                __builtin_nontemporal_store(sacc[idx], &yf[(size_t)o * N_NODES + n]);
        }
    }

    // stats from summed buffer (wave0 only), striped over NSLOTS buffers
    if (wid == 0) {
        int slot = blockIdx.x & (NSLOTS - 1);
#pragma unroll
        for (int m = 0; m < 4; ++m) {
#pragma unroll
            for (int r = 0; r < 4; ++r) {
                int o = m * 16 + quad * 4 + r;
                float s = 0.f, sq = 0.f;
#pragma unroll
                for (int g = 0; g < 2; ++g) {
                    float v = sacc[o * 32 + g * 16 + l15];
                    s += v;
                    sq += v * v;
                }
#pragma unroll
                for (int d = 1; d < 16; d <<= 1) {
                    s += __shfl_xor(s, d);
                    sq += __shfl_xor(sq, d);
                }
                if (l15 == 0) {
                    atomicAdd(&stats[slot * 128 + o], s);
                    atomicAdd(&stats[slot * 128 + 64 + o], sq);
                }
            }
        }
    }
}

// ---------------------------------------------------------------------------
// Kernel 3: finalize stats + BN + ReLU. Grid (10, 64), grid-stride per channel.
// bf16 path: stream yb (nt loads) -> fp32 d_out (nt stores).
// ---------------------------------------------------------------------------
__global__ __launch_bounds__(256) void k_bn_relu(const ushort* __restrict__ yb,
                                                 float* __restrict__ out,
                                                 const float* __restrict__ stats,
                                                 const float* __restrict__ gamma,
                                                 const float* __restrict__ beta,
                                                 int use_bf16) {
    __shared__ float s_sc, s_sh;
    int t = threadIdx.x;
    int o = blockIdx.y;
    if (t < 32) {
        float s = stats[t * 128 + o];
        float sq = stats[t * 128 + 64 + o];
#pragma unroll
        for (int d = 1; d < 32; d <<= 1) {
            s += __shfl_xor(s, d);
            sq += __shfl_xor(sq, d);
        }
        if (t == 0) {
            const float invN = 1.0f / (float)N_NODES;
            float mean = s * invN;
            float var = sq * invN - mean * mean;
            float rstd = rsqrtf(var + 1e-3f);
            float sc = gamma[o] * rstd;
            s_sc = sc;
            s_sh = beta[o] - mean * sc;
        }
    }
    __syncthreads();
    float sc = s_sc, sh = s_sh;
    if (use_bf16) {
        const u32x4* row = reinterpret_cast<const u32x4*>(yb + (size_t)o * Y_STRIDE);
        f32x4* orow = reinterpret_cast<f32x4*>(out + (size_t)o * N_NODES);
        for (int c = blockIdx.x * 256 + t; c < CHUNKS_PER_ROW; c += BN_XBLOCKS * 256) {
            u32x4 v = __builtin_nontemporal_load(row + c);
            f32x4 f0, f1;
#pragma unroll
            for (int j = 0; j < 2; ++j) {
                f0[2 * j] = __uint_as_float(v[j] << 16);
                f0[2 * j + 1] = __uint_as_float(v[j] & 0xffff0000u);
                f1[2 * j] = __uint_as_float(v[j + 2] << 16);
                f1[2 * j + 1] = __uint_as_float(v[j + 2] & 0xffff0000u);
            }
#pragma unroll
            for (int j = 0; j < 4; ++j) {
                f0[j] = fmaxf(fmaf(f0[j], sc, sh), 0.f);
                f1[j] = fmaxf(fmaf(f1[j], sc, sh), 0.f);
            }
            __builtin_nontemporal_store(f0, orow + 2 * c);
            __builtin_nontemporal_store(f1, orow + 2 * c + 1);
        }
    } else {
        float4* row = reinterpret_cast<float4*>(out + (size_t)o * N_NODES);
        for (int i = blockIdx.x * 256 + t; i < N_NODES / 4; i += BN_XBLOCKS * 256) {
            float4 v = row[i];
            v.x = fmaxf(fmaf(v.x, sc, sh), 0.f);
            v.y = fmaxf(fmaf(v.y, sc, sh), 0.f);
            v.z = fmaxf(fmaf(v.z, sc, sh), 0.f);
            v.w = fmaxf(fmaf(v.w, sc, sh), 0.f);
            row[i] = v;
        }
    }
}

extern "C" void kernel_launch(void* const* d_in, const int* in_sizes, int n_in,
                              void* d_out, int out_size, void* d_ws, size_t ws_size,
                              hipStream_t stream) {
    const float* data_in = (const float*)d_in[0];
    const int* neigh = (const int*)d_in[1];
    const float* W = (const float*)d_in[2];
    const float* gamma = (const float*)d_in[3];
    const float* beta = (const float*)d_in[4];
    float* out = (float*)d_out;

    char* ws = (char*)d_ws;
    ushort* xT = (ushort*)ws;                     // 150016*32*2 = 9,601,024 B
    ushort* A_frag = (ushort*)(ws + 9601024);     // 64*32*28*2  =   114,688 B
    float* stats = (float*)(ws + 9715712);        // 32*128 partials (+pad) = 16,896 B
    ushort* yb = (ushort*)(ws + 9732608);         // 64*150016*2 = 19,202,048 B

    int use_bf16 = (ws_size >= WS_NEED) ? 1 : 0;

    k_prep<<<TRANS_BLOCKS + WPREP_BLOCKS, 256, 0, stream>>>(data_in, xT, W, A_frag,
                                                            stats);
    k_conv<<<CONV_BLOCKS, 256, 0, stream>>>(xT, A_frag, neigh, out, yb, stats,
                                            use_bf16);
    k_bn_relu<<<dim3(BN_XBLOCKS, C_OUT), 256, 0, stream>>>(yb, out, stats, gamma,
                                                           beta, use_bf16);
}